// Round 2
// baseline (571.061 us; speedup 1.0000x reference)
//
#include <hip/hip_runtime.h>
#include <hip/hip_fp16.h>

#define HH 8
#define BB 256
#define SS 64
#define EE 256
#define DH 32
#define DD 2048   // S*d

typedef _Float16 f16x8 __attribute__((ext_vector_type(8)));
typedef _Float16 f16x4 __attribute__((ext_vector_type(4)));
typedef float f32x4v __attribute__((ext_vector_type(4)));

#define BM 256
#define BN 128
#define BK 64
#define LDK 72   // padded LDS row stride (halfs): 144B -> 2-way bank aliasing max (free)

// One block per (proj p, head h, N-tile). BM=256 = full batch M, so every
// weight element is fetched from HBM exactly once (no cross-XCD re-read).
__global__ __launch_bounds__(512, 4)
void qkv_kernel(const float* __restrict__ dec, const float* __restrict__ enc,
                const float* __restrict__ WQ, const float* __restrict__ bQ,
                const float* __restrict__ WK, const float* __restrict__ bK,
                const float* __restrict__ WV, const float* __restrict__ bV,
                __half* __restrict__ qkv)
{
    __shared__ _Float16 Asm[BM][LDK];
    __shared__ _Float16 Bsm[BN][LDK];

    const int z = blockIdx.z;
    const int p = z >> 3;           // 0:Q 1:K 2:V
    const int h = z & 7;
    const float* __restrict__ x    = (p == 0) ? dec : enc;
    const float* __restrict__ W    = (p == 0) ? WQ : (p == 1) ? WK : WV;
    const float* __restrict__ bias = (p == 0) ? bQ : (p == 1) ? bK : bV;
    const float* __restrict__ Wh = W + (size_t)h * DD * DD;
    const float* __restrict__ bh = bias + h * DD;
    const int n0 = blockIdx.x * BN;

    const int tid  = threadIdx.x;
    const int lane = tid & 63;
    const int wave = tid >> 6;      // 0..7
    const int wm = wave & 3;        // 4 waves along M (64 rows each)
    const int wn = wave >> 2;       // 2 waves along N (64 cols each)

    f32x4v acc[4][4];
    #pragma unroll
    for (int m = 0; m < 4; ++m)
        #pragma unroll
        for (int n = 0; n < 4; ++n)
            acc[m][n] = (f32x4v){0.f, 0.f, 0.f, 0.f};

    const int rrow = lane & 15;     // A row / B col within 16x16 frag
    const int kg   = lane >> 4;     // k-group: 8 contiguous k elems per lane

    for (int k0 = 0; k0 < DD; k0 += BK) {
        // ---- stage A: x gathered per head, 256 rows x 64 k (fp32 -> fp16) ----
        // x[h][b][i] = in[b*S*E + (i>>5)*E + h*32 + (i&31)]
        #pragma unroll
        for (int r = 0; r < 8; ++r) {
            int g   = r * 512 + tid;
            int row = g >> 4;            // 16 float4 per row
            int k   = (g & 15) * 4;
            const float4 v = *(const float4*)(x + (size_t)row * (SS * EE)
                                + ((k0 + k) >> 5) * EE + h * DH + (k & 31));
            f16x4 hv = { (_Float16)v.x, (_Float16)v.y, (_Float16)v.z, (_Float16)v.w };
            *(f16x4*)&Asm[row][k] = hv;
        }
        // ---- stage B: weights W[h][o][k], 128 rows x 64 k ----
        #pragma unroll
        for (int r = 0; r < 4; ++r) {
            int g   = r * 512 + tid;
            int row = g >> 4;
            int k   = (g & 15) * 4;
            const float4 v = *(const float4*)(Wh + (size_t)(n0 + row) * DD + k0 + k);
            f16x4 hv = { (_Float16)v.x, (_Float16)v.y, (_Float16)v.z, (_Float16)v.w };
            *(f16x4*)&Bsm[row][k] = hv;
        }
        __syncthreads();

        #pragma unroll
        for (int ks = 0; ks < 2; ++ks) {
            f16x8 af[4], bf[4];
            const int kofs = ks * 32 + kg * 8;
            #pragma unroll
            for (int m = 0; m < 4; ++m)
                af[m] = *(const f16x8*)&Asm[wm * 64 + m * 16 + rrow][kofs];
            #pragma unroll
            for (int n = 0; n < 4; ++n)
                bf[n] = *(const f16x8*)&Bsm[wn * 64 + n * 16 + rrow][kofs];
            #pragma unroll
            for (int m = 0; m < 4; ++m)
                #pragma unroll
                for (int n = 0; n < 4; ++n)
                    acc[m][n] = __builtin_amdgcn_mfma_f32_16x16x32_f16(af[m], bf[n], acc[m][n], 0, 0, 0);
        }
        __syncthreads();
    }

    // ---- epilogue: add bias, store fp16 to workspace qkv[p][h][b][o] ----
    __half* __restrict__ P = qkv + ((size_t)p * HH + h) * BB * DD;
    const int cg = lane >> 4;
    const int cl = lane & 15;
    #pragma unroll
    for (int n = 0; n < 4; ++n) {
        const int col = n0 + wn * 64 + n * 16 + cl;
        const float bv = bh[col];
        #pragma unroll
        for (int m = 0; m < 4; ++m) {
            const int row = wm * 64 + m * 16 + cg * 4;   // C/D: row=(lane>>4)*4+j
            #pragma unroll
            for (int j = 0; j < 4; ++j)
                P[(size_t)(row + j) * DD + col] = (__half)(acc[m][n][j] + bv);
        }
    }
}

// One wave per (h,b). Softmax is over the QUERY axis (axis=2): thread k owns
// scores column [:,k] in registers -> per-thread max/exp/sum IS the softmax.
// Then transpose attn through LDS and let thread q do the PV accumulation.
__global__ __launch_bounds__(64, 1)
void attn_kernel(const __half* __restrict__ qkv, float* __restrict__ out)
{
    __shared__ float Qf[SS][DH + 4];   // +4 pad: write banks spread
    __shared__ float Vf[SS][DH + 4];
    __shared__ float At[SS][SS + 4];   // attn^T [k][q]; stride 68 floats (16B-aligned rows)

    const int hb = blockIdx.x;
    const int h  = hb >> 8;
    const int b  = hb & 255;
    const int lane = threadIdx.x;

    const __half* __restrict__ Qp = qkv + ((size_t)(0 * HH + h) * BB + b) * DD;
    const __half* __restrict__ Kp = qkv + ((size_t)(1 * HH + h) * BB + b) * DD;
    const __half* __restrict__ Vp = qkv + ((size_t)(2 * HH + h) * BB + b) * DD;

    // K row 'lane' into registers; Q,V rows into LDS (fp32)
    float kreg[DH];
    {
        const f16x8* kr = (const f16x8*)(Kp + lane * DH);
        #pragma unroll
        for (int i = 0; i < 4; ++i) {
            f16x8 v = kr[i];
            #pragma unroll
            for (int j = 0; j < 8; ++j) kreg[i * 8 + j] = (float)v[j];
        }
        const f16x8* qr = (const f16x8*)(Qp + lane * DH);
        #pragma unroll
        for (int i = 0; i < 4; ++i) {
            f16x8 v = qr[i];
            #pragma unroll
            for (int j = 0; j < 8; ++j) Qf[lane][i * 8 + j] = (float)v[j];
        }
        const f16x8* vr = (const f16x8*)(Vp + lane * DH);
        #pragma unroll
        for (int i = 0; i < 4; ++i) {
            f16x8 v = vr[i];
            #pragma unroll
            for (int j = 0; j < 8; ++j) Vf[lane][i * 8 + j] = (float)v[j];
        }
    }
    __syncthreads();

    // scores[q][k=lane] for all q — Q reads are wave-uniform (broadcast, conflict-free)
    float sc[SS];
    #pragma unroll
    for (int q = 0; q < SS; ++q) {
        float s = 0.f;
        #pragma unroll
        for (int d4 = 0; d4 < DH / 4; ++d4) {
            float4 qv = *(const float4*)&Qf[q][d4 * 4];
            s += qv.x * kreg[d4 * 4 + 0] + qv.y * kreg[d4 * 4 + 1]
               + qv.z * kreg[d4 * 4 + 2] + qv.w * kreg[d4 * 4 + 3];
        }
        sc[q] = s;
    }

    // softmax over q (per-thread, thread = k)
    float mx = sc[0];
    #pragma unroll
    for (int q = 1; q < SS; ++q) mx = fmaxf(mx, sc[q]);
    float sum = 0.f;
    #pragma unroll
    for (int q = 0; q < SS; ++q) { sc[q] = __expf(sc[q] - mx); sum += sc[q]; }
    const float inv = 0.17677669529663687f / sum;   // fold 1/sqrt(32) into weights

    #pragma unroll
    for (int q4 = 0; q4 < SS / 4; ++q4) {
        float4 w = { sc[q4 * 4 + 0] * inv, sc[q4 * 4 + 1] * inv,
                     sc[q4 * 4 + 2] * inv, sc[q4 * 4 + 3] * inv };
        *(float4*)&At[lane][q4 * 4] = w;
    }
    __syncthreads();

    // PV: thread = q. At[k][lane] reads are conflict-free (stride 68 floats).
    float z[DH];
    #pragma unroll
    for (int d = 0; d < DH; ++d) z[d] = 0.f;
    #pragma unroll
    for (int k = 0; k < SS; ++k) {
        const float a = At[k][lane];
        #pragma unroll
        for (int d4 = 0; d4 < DH / 4; ++d4) {
            float4 vv = *(const float4*)&Vf[k][d4 * 4];
            z[d4 * 4 + 0] += a * vv.x;
            z[d4 * 4 + 1] += a * vv.y;
            z[d4 * 4 + 2] += a * vv.z;
            z[d4 * 4 + 3] += a * vv.w;
        }
    }

    // out[b][s=lane][h*32+d]
    float* __restrict__ op = out + (size_t)b * (SS * EE) + (size_t)lane * EE + h * DH;
    #pragma unroll
    for (int d4 = 0; d4 < DH / 4; ++d4) {
        float4 w = { z[d4 * 4 + 0], z[d4 * 4 + 1], z[d4 * 4 + 2], z[d4 * 4 + 3] };
        *(float4*)&op[d4 * 4] = w;
    }
}

extern "C" void kernel_launch(void* const* d_in, const int* in_sizes, int n_in,
                              void* d_out, int out_size, void* d_ws, size_t ws_size,
                              hipStream_t stream)
{
    const float* dec = (const float*)d_in[0];
    const float* enc = (const float*)d_in[1];
    const float* WQ  = (const float*)d_in[2];
    const float* bQ  = (const float*)d_in[3];
    const float* WK  = (const float*)d_in[4];
    const float* bK  = (const float*)d_in[5];
    const float* WV  = (const float*)d_in[6];
    const float* bV  = (const float*)d_in[7];
    __half* qkv = (__half*)d_ws;     // 3*8*256*2048 fp16 = 25.2 MB
    float* out = (float*)d_out;

    dim3 grid1(DD / BN, 1, 3 * HH);  // 16 x 1 x 24 = 384 blocks
    qkv_kernel<<<grid1, dim3(512, 1, 1), 0, stream>>>(dec, enc, WQ, bQ, WK, bK, WV, bV, qkv);
    attn_kernel<<<dim3(HH * BB, 1, 1), dim3(64, 1, 1), 0, stream>>>(qkv, out);
}